// Round 1
// baseline (301.508 us; speedup 1.0000x reference)
//
#include <hip/hip_runtime.h>

#define IMG_W 2048
#define IMG_H 2048
#define OUT_W 2044
#define OUT_H 2044
#define OUT_HW (2044 * 2044)

// Workgroup output tile: TI rows x TJ cols, 14 d-planes deep.
#define TI 16
#define TJ 64
#define LR (TI + 4)   // staged input rows
#define LC (TJ + 4)   // staged input cols
#define LSTR 69       // LDS row stride in 16B pixel-records (padded: 69*16B -> 20-bank row shift)

typedef int v4i __attribute__((ext_vector_type(4)));

// Build MFMA A-fragments from weights.
// GEMM: D[m][n] = sum_k A[m][k] * B[k][n]
//   m = output channel d (0..13, rows 14/15 zero)
//   k = (pair p, bit-plane c): p = 4t + (lane>>4) over 7 chunks t (25 real (kh,kw) pairs + 3 pad)
//   A[m][(p,c)] = w8[kd = c - m][kh][kw] for 0 <= c-m <= 2, else 0;  w8 = rint(w*255)
// Nibble split (signed-i8 safety): alo = w8 & 15, ahi = w8 >> 4; recombine 16*hi + lo (exact).
// Fragment packing: lane l (m = l&15, g = l>>4), chunk t: 16 bytes, byte e = c index e.
// The same (group, byte) packing is used for B, so any HW within-lane k permutation cancels.
__global__ void quant_frag(const float* __restrict__ w, v4i* __restrict__ wfrag) {
    const int l = threadIdx.x;
    const int m = l & 15, g = l >> 4;
    #pragma unroll
    for (int t = 0; t < 7; ++t) {
        const int p = 4 * t + g;
        unsigned lo[4] = {0, 0, 0, 0}, hi[4] = {0, 0, 0, 0};
        if (p < 25 && m < 14) {
            const int kh = p / 5, kw = p % 5;
            #pragma unroll
            for (int kd = 0; kd < 3; ++kd) {
                const int e = m + kd;                       // c = m + kd  (<= 15)
                const unsigned w8 = (unsigned)(int)rintf(w[(kd * 5 + kh) * 5 + kw] * 255.0f);
                lo[e >> 2] |= (w8 & 15u) << (8 * (e & 3));
                hi[e >> 2] |= (w8 >> 4)  << (8 * (e & 3));
            }
        }
        v4i vlo, vhi;
        vlo.x = (int)lo[0]; vlo.y = (int)lo[1]; vlo.z = (int)lo[2]; vlo.w = (int)lo[3];
        vhi.x = (int)hi[0]; vhi.y = (int)hi[1]; vhi.z = (int)hi[2]; vhi.w = (int)hi[3];
        wfrag[t * 64 + l]       = vlo;
        wfrag[448 + t * 64 + l] = vhi;
    }
}

// Bit-expand the input tile pixel-major into LDS (16 bytes/pixel = its 16 bit-planes),
// then im2col-from-LDS: one ds_read_b128 per lane = full B-fragment for one
// mfma_i32_16x16x64_i8 (16 channels x 16 pixels x K=64 = 4 (kh,kw) pairs x 16 planes).
__global__ __launch_bounds__(256, 3) void conv_mfma(
        const int* __restrict__ x, const v4i* __restrict__ wfrag,
        const float* __restrict__ bias, float* __restrict__ out) {
    __shared__ v4i vt[LR * LSTR];
    const int tid  = threadIdx.x;
    const int lane = tid & 63;
    const int wv   = tid >> 6;     // wave 0..3
    const int m16  = lane & 15;    // pixel-in-group (B) / channel (A,D rows via g4)
    const int g4   = lane >> 4;    // k-subgroup / D row-block
    const int I0 = blockIdx.y * TI;
    const int J0 = blockIdx.x * TJ;

    // A-fragments: issue global loads first so they overlap the staging phase.
    v4i alo[7], ahi[7];
    #pragma unroll
    for (int t = 0; t < 7; ++t) {
        alo[t] = wfrag[t * 64 + lane];
        ahi[t] = wfrag[448 + t * 64 + lane];
    }
    const float b0 = bias[0];

    // ---- stage + bit-expand LR x LC pixels ----
    #pragma unroll
    for (int rr = 0; rr < 5; ++rr) {
        const int r  = wv + rr * 4;                        // 0..19
        const int gr = min(I0 + r, IMG_H - 1);             // clamp (only feeds masked outputs)
        const long rowoff = (long)gr * IMG_W;
        #pragma unroll
        for (int cc = 0; cc < 2; ++cc) {
            const int col = lane + cc * 64;
            if (col < LC) {
                const int gc = min(J0 + col, IMG_W - 1);
                const unsigned v = (unsigned)x[rowoff + gc];
                v4i e;  // byte c of record = bit c of pixel
                e.x = (int)(__umul24( v         & 0xFu, 0x00204081u) & 0x01010101u);
                e.y = (int)(__umul24((v >> 4)   & 0xFu, 0x00204081u) & 0x01010101u);
                e.z = (int)(__umul24((v >> 8)   & 0xFu, 0x00204081u) & 0x01010101u);
                e.w = (int)(__umul24((v >> 12)  & 0xFu, 0x00204081u) & 0x01010101u);
                vt[r * LSTR + col] = e;
            }
        }
    }
    __syncthreads();

    // Per-lane k-chunk offsets: pair p = 4t + g4 -> (kh,kw); pads point at (0,0), weights=0.
    int koff[7];
    #pragma unroll
    for (int t = 0; t < 7; ++t) {
        const int p  = 4 * t + g4;
        const int kh = (p < 25) ? (p / 5) : 0;
        const int kw = (p < 25) ? (p - kh * 5) : 0;
        koff[t] = kh * LSTR + kw;
    }

    const float scale = 1.0f / 255.0f;

    // ---- MFMA phase: wave wv owns local rows 4wv..4wv+3, 4 column-groups of 16 ----
    #pragma unroll 1
    for (int ig = 0; ig < 4; ++ig) {
        const int il = wv * 4 + ig;
        const int i  = I0 + il;
        #pragma unroll 1
        for (int jg = 0; jg < 4; ++jg) {
            const int jb    = jg * 16 + m16;
            const int gbase = il * LSTR + jb;
            v4i bf[7];
            #pragma unroll
            for (int t = 0; t < 7; ++t) bf[t] = vt[gbase + koff[t]];

            v4i al0 = {0,0,0,0}, al1 = {0,0,0,0}, ah0 = {0,0,0,0}, ah1 = {0,0,0,0};
            #pragma unroll
            for (int t = 0; t < 6; t += 2) {   // two chains for MFMA-latency ILP
                al0 = __builtin_amdgcn_mfma_i32_16x16x64_i8(alo[t],     bf[t],     al0, 0, 0, 0);
                ah0 = __builtin_amdgcn_mfma_i32_16x16x64_i8(ahi[t],     bf[t],     ah0, 0, 0, 0);
                al1 = __builtin_amdgcn_mfma_i32_16x16x64_i8(alo[t + 1], bf[t + 1], al1, 0, 0, 0);
                ah1 = __builtin_amdgcn_mfma_i32_16x16x64_i8(ahi[t + 1], bf[t + 1], ah1, 0, 0, 0);
            }
            al0 = __builtin_amdgcn_mfma_i32_16x16x64_i8(alo[6], bf[6], al0, 0, 0, 0);
            ah0 = __builtin_amdgcn_mfma_i32_16x16x64_i8(ahi[6], bf[6], ah0, 0, 0, 0);

            // D layout (verified, dtype-independent): col = lane&15 = pixel, row = g4*4+r = channel
            const int j = J0 + jb;
            if (i < OUT_H && j < OUT_W) {
                #pragma unroll
                for (int r = 0; r < 4; ++r) {
                    const int d = g4 * 4 + r;
                    if (d < 14) {
                        const int acc = (ah0[r] + ah1[r]) * 16 + (al0[r] + al1[r]);
                        out[(size_t)d * OUT_HW + (size_t)i * OUT_W + j] =
                            fmaf((float)acc, scale, b0);
                    }
                }
            }
        }
    }
}

extern "C" void kernel_launch(void* const* d_in, const int* in_sizes, int n_in,
                              void* d_out, int out_size, void* d_ws, size_t ws_size,
                              hipStream_t stream) {
    const int* x      = (const int*)d_in[0];
    const float* w    = (const float*)d_in[1];
    const float* bias = (const float*)d_in[2];
    float* out        = (float*)d_out;
    v4i* wfrag        = (v4i*)d_ws;   // 896 * 16B = 14336 B of workspace

    quant_frag<<<1, 64, 0, stream>>>(w, wfrag);
    conv_mfma<<<dim3((OUT_W + TJ - 1) / TJ, (OUT_H + TI - 1) / TI), 256, 0, stream>>>(
        x, wfrag, bias, out);
}

// Round 2
// 300.633 us; speedup vs baseline: 1.0029x; 1.0029x over previous
//
#include <hip/hip_runtime.h>

#define IMG_W 2048
#define IMG_H 2048
#define OUT_W 2044
#define OUT_H 2044
#define OUT_HW (2044 * 2044)

// Workgroup output tile: TI rows x TJ cols, 14 d-planes deep.
#define TI 16
#define TJ 64
#define LR (TI + 4)   // staged input rows
#define LC (TJ + 4)   // staged input cols
#define LSTR 69       // LDS row stride in 16B pixel-records

typedef int v4i __attribute__((ext_vector_type(4)));

// Build MFMA A-fragments from weights (unchanged — verified bit-exact, absmax 0.125).
// GEMM: D[m][n] = sum_k A[m][k]*B[k][n]; m = channel d, k = (pair p, bit-plane c),
// p = 4t + (lane>>4) over 7 chunks (25 real (kh,kw) pairs + 3 zero pads).
// Nibble split keeps operands signed-i8-safe; recombine 16*hi + lo exactly.
__global__ void quant_frag(const float* __restrict__ w, v4i* __restrict__ wfrag) {
    const int l = threadIdx.x;
    const int m = l & 15, g = l >> 4;
    #pragma unroll
    for (int t = 0; t < 7; ++t) {
        const int p = 4 * t + g;
        unsigned lo[4] = {0, 0, 0, 0}, hi[4] = {0, 0, 0, 0};
        if (p < 25 && m < 14) {
            const int kh = p / 5, kw = p % 5;
            #pragma unroll
            for (int kd = 0; kd < 3; ++kd) {
                const int e = m + kd;
                const unsigned w8 = (unsigned)(int)rintf(w[(kd * 5 + kh) * 5 + kw] * 255.0f);
                lo[e >> 2] |= (w8 & 15u) << (8 * (e & 3));
                hi[e >> 2] |= (w8 >> 4)  << (8 * (e & 3));
            }
        }
        v4i vlo, vhi;
        vlo.x = (int)lo[0]; vlo.y = (int)lo[1]; vlo.z = (int)lo[2]; vlo.w = (int)lo[3];
        vhi.x = (int)hi[0]; vhi.y = (int)hi[1]; vhi.z = (int)hi[2]; vhi.w = (int)hi[3];
        wfrag[t * 64 + l]       = vlo;
        wfrag[448 + t * 64 + l] = vhi;
    }
}

// Pixel-major bit-expansion in LDS (16 B/pixel = 16 bit-planes), im2col via one
// ds_read_b128 per lane per k-chunk. This version software-pipelines the 16
// per-wave output groups with two named B-fragment buffers so the 7 LDS reads
// of iteration n+1 hide under the 13 MFMAs of iteration n.
__global__ __launch_bounds__(256, 2) void conv_mfma(
        const int* __restrict__ x, const v4i* __restrict__ wfrag,
        const float* __restrict__ bias, float* __restrict__ out) {
    __shared__ v4i vt[LR * LSTR];
    const int tid  = threadIdx.x;
    const int lane = tid & 63;
    const int wv   = tid >> 6;     // wave 0..3
    const int m16  = lane & 15;    // pixel-in-group (B) / channel row (A)
    const int g4   = lane >> 4;    // k-subgroup / D row-block
    const int I0 = blockIdx.y * TI;
    const int J0 = blockIdx.x * TJ;

    // A-fragments: global loads issue first, overlap the staging phase.
    v4i alo[7], ahi[7];
    #pragma unroll
    for (int t = 0; t < 7; ++t) {
        alo[t] = wfrag[t * 64 + lane];
        ahi[t] = wfrag[448 + t * 64 + lane];
    }
    const float b0 = bias[0];

    // ---- stage + bit-expand LR x LC pixels ----
    #pragma unroll
    for (int rr = 0; rr < 5; ++rr) {
        const int r  = wv + rr * 4;                        // 0..19
        const int gr = min(I0 + r, IMG_H - 1);
        const long rowoff = (long)gr * IMG_W;
        #pragma unroll
        for (int cc = 0; cc < 2; ++cc) {
            const int col = lane + cc * 64;
            if (col < LC) {
                const int gc = min(J0 + col, IMG_W - 1);
                const unsigned v = (unsigned)x[rowoff + gc];
                v4i e;  // byte c of record = bit c of pixel
                e.x = (int)(__umul24( v         & 0xFu, 0x00204081u) & 0x01010101u);
                e.y = (int)(__umul24((v >> 4)   & 0xFu, 0x00204081u) & 0x01010101u);
                e.z = (int)(__umul24((v >> 8)   & 0xFu, 0x00204081u) & 0x01010101u);
                e.w = (int)(__umul24((v >> 12)  & 0xFu, 0x00204081u) & 0x01010101u);
                vt[r * LSTR + col] = e;
            }
        }
    }
    __syncthreads();

    // Per-lane k-chunk record offsets (pads -> (0,0), weights are zero there).
    int koff[7];
    #pragma unroll
    for (int t = 0; t < 7; ++t) {
        const int p  = 4 * t + g4;
        const int kh = (p < 25) ? (p / 5) : 0;
        const int kw = (p < 25) ? (p - kh * 5) : 0;
        koff[t] = kh * LSTR + kw;
    }

    const float scale = 1.0f / 255.0f;

    // it in 0..15: ig = it>>2 (row within wave's 4-row band), jg = it&3 (16-col group)
    auto LOADB = [&](v4i* bf, int it) {
        const int rec = (wv * 4 + (it >> 2)) * LSTR + (it & 3) * 16 + m16;
        #pragma unroll
        for (int t = 0; t < 7; ++t) bf[t] = vt[rec + koff[t]];
    };

    auto COMPUTE = [&](const v4i* bf, int it) {
        v4i al0 = {0,0,0,0}, al1 = {0,0,0,0}, ah0 = {0,0,0,0}, ah1 = {0,0,0,0};
        #pragma unroll
        for (int t = 0; t < 6; t += 2) {   // 4 interleaved chains for MFMA ILP
            al0 = __builtin_amdgcn_mfma_i32_16x16x64_i8(alo[t],     bf[t],     al0, 0, 0, 0);
            ah0 = __builtin_amdgcn_mfma_i32_16x16x64_i8(ahi[t],     bf[t],     ah0, 0, 0, 0);
            al1 = __builtin_amdgcn_mfma_i32_16x16x64_i8(alo[t + 1], bf[t + 1], al1, 0, 0, 0);
            ah1 = __builtin_amdgcn_mfma_i32_16x16x64_i8(ahi[t + 1], bf[t + 1], ah1, 0, 0, 0);
        }
        al0 = __builtin_amdgcn_mfma_i32_16x16x64_i8(alo[6], bf[6], al0, 0, 0, 0);
        ah0 = __builtin_amdgcn_mfma_i32_16x16x64_i8(ahi[6], bf[6], ah0, 0, 0, 0);

        // D layout: col = lane&15 = pixel j, row = g4*4 + r = channel d
        const int i = I0 + wv * 4 + (it >> 2);
        const int j = J0 + (it & 3) * 16 + m16;
        if (i < OUT_H && j < OUT_W) {
            float* o = out + (size_t)(g4 * 4) * OUT_HW + (size_t)i * OUT_W + j;
            #pragma unroll
            for (int r = 0; r < 4; ++r) {
                if (r < 2 || g4 < 3) {     // d = g4*4 + r < 14
                    const int acc = (ah0[r] + ah1[r]) * 16 + (al0[r] + al1[r]);
                    o[(size_t)r * OUT_HW] = fmaf((float)acc, scale, b0);
                }
            }
        }
    };

    // 1-deep software pipeline over the 16 output groups (named buffers, static
    // indexing only — no runtime-indexed arrays).
    v4i bA[7], bB[7];
    LOADB(bA, 0);
    #pragma unroll 1
    for (int h = 0; h < 8; ++h) {
        const int it0 = 2 * h;
        LOADB(bB, it0 + 1);          // prefetch odd iteration
        COMPUTE(bA, it0);            // MFMAs hide the ds_read latency above
        if (h < 7) LOADB(bA, it0 + 2);  // prefetch next even iteration
        COMPUTE(bB, it0 + 1);
    }
}

extern "C" void kernel_launch(void* const* d_in, const int* in_sizes, int n_in,
                              void* d_out, int out_size, void* d_ws, size_t ws_size,
                              hipStream_t stream) {
    const int* x      = (const int*)d_in[0];
    const float* w    = (const float*)d_in[1];
    const float* bias = (const float*)d_in[2];
    float* out        = (float*)d_out;
    v4i* wfrag        = (v4i*)d_ws;   // 896 * 16B = 14336 B of workspace

    quant_frag<<<1, 64, 0, stream>>>(w, wfrag);
    conv_mfma<<<dim3((OUT_W + TJ - 1) / TJ, (OUT_H + TI - 1) / TI), 256, 0, stream>>>(
        x, wfrag, bias, out);
}